// Round 2
// baseline (3232.737 us; speedup 1.0000x reference)
//
#include <hip/hip_runtime.h>
#include <hip/hip_bf16.h>

#define NN 20000
#define NE 600000
#define DIN 128
#define DD 64
#define HH 4
#define DKK 16
#define LL 4
#define TT 3
#define RR 32

// ---- monotone float<->uint encoding for atomicMax on signed floats ----
__device__ __forceinline__ unsigned enc_f(float x) {
    unsigned b = __float_as_uint(x);
    return (b & 0x80000000u) ? ~b : (b | 0x80000000u);
}
__device__ __forceinline__ float dec_f(unsigned u) {
    unsigned b = (u & 0x80000000u) ? (u & 0x7fffffffu) : ~u;
    return __uint_as_float(b);
}

__device__ __forceinline__ int src_nt(int e) { return e <= 9 ? 0 : (e <= 21 ? 1 : 2); }
__device__ __forceinline__ int dst_nt(int e) {
    if (e <= 2 || (e >= 10 && e <= 13) || (e >= 22 && e <= 24)) return 0;
    if ((e >= 3 && e <= 6) || (e >= 14 && e <= 17) || (e >= 25 && e <= 28)) return 1;
    return 2;
}

// ---- x = tanh(h @ adapt_W[ntype] + adapt_b[ntype]); wave per node ----
__global__ void adapt_kernel(const float* __restrict__ h, const int* __restrict__ ntype,
                             const float* __restrict__ W, const float* __restrict__ b,
                             float* __restrict__ x) {
    int wid = (blockIdx.x * blockDim.x + threadIdx.x) >> 6;
    int lane = threadIdx.x & 63;
    if (wid >= NN) return;
    int t = ntype[wid];
    const float* Wt = W + (size_t)t * DIN * DD;
    float h0 = h[(size_t)wid * DIN + lane];
    float h1 = h[(size_t)wid * DIN + 64 + lane];
    float acc = b[t * DD + lane];
#pragma unroll
    for (int d = 0; d < 64; ++d) {
        acc += __shfl(h0, d) * Wt[d * DD + lane];
    }
#pragma unroll
    for (int d = 0; d < 64; ++d) {
        acc += __shfl(h1, d) * Wt[(64 + d) * DD + lane];
    }
    x[(size_t)wid * DD + lane] = tanhf(acc);
}

// ---- k,q,v = x @ W*[ntype] + b*[ntype]; wave per node ----
__global__ void kqv_kernel(const float* __restrict__ x, const int* __restrict__ ntype,
                           const float* __restrict__ Wk, const float* __restrict__ bk,
                           const float* __restrict__ Wq, const float* __restrict__ bq,
                           const float* __restrict__ Wv, const float* __restrict__ bv,
                           float* __restrict__ k, float* __restrict__ q, float* __restrict__ v) {
    int wid = (blockIdx.x * blockDim.x + threadIdx.x) >> 6;
    int lane = threadIdx.x & 63;
    if (wid >= NN) return;
    int t = ntype[wid];
    const float* Wkt = Wk + (size_t)t * DD * DD;
    const float* Wqt = Wq + (size_t)t * DD * DD;
    const float* Wvt = Wv + (size_t)t * DD * DD;
    float xv = x[(size_t)wid * DD + lane];
    float ak = bk[t * DD + lane];
    float aq = bq[t * DD + lane];
    float av = bv[t * DD + lane];
#pragma unroll
    for (int d = 0; d < 64; ++d) {
        float xd = __shfl(xv, d);
        ak += xd * Wkt[d * DD + lane];
        aq += xd * Wqt[d * DD + lane];
        av += xd * Wvt[d * DD + lane];
    }
    k[(size_t)wid * DD + lane] = ak;
    q[(size_t)wid * DD + lane] = aq;
    v[(size_t)wid * DD + lane] = av;
}

// ---- transpose rel matrices: [l][r][h][d][f] -> [l][r][h][f][d] (both tensors) ----
__global__ void transpose_rel_kernel(const float* __restrict__ relA, const float* __restrict__ relM,
                                     float* __restrict__ AT, float* __restrict__ MT) {
    int idx = blockIdx.x * blockDim.x + threadIdx.x;
    if (idx >= LL * RR * HH * 256) return;
    int sidx = (idx & ~255) + ((idx & 15) << 4) + ((idx >> 4) & 15);
    AT[idx] = relA[sidx];
    MT[idx] = relM[sidx];
}

// ---- k_rel/v_rel precompute: wave per node, loop over all 32 etypes ----
__global__ void relpre_kernel(const float* __restrict__ k, const float* __restrict__ v,
                              const float* __restrict__ AT, const float* __restrict__ MT,
                              __hip_bfloat16* __restrict__ k_rel, __hip_bfloat16* __restrict__ v_rel) {
    int n = (blockIdx.x * blockDim.x + threadIdx.x) >> 6;
    int lane = threadIdx.x & 63;
    if (n >= NN) return;
    float kv = k[(size_t)n * DD + lane];
    float vv = v[(size_t)n * DD + lane];
    int base = lane & 48;
    float kd[16], vd[16];
#pragma unroll
    for (int j = 0; j < 16; ++j) {
        kd[j] = __shfl(kv, base + j);
        vd[j] = __shfl(vv, base + j);
    }
    int hh = lane >> 4, f = lane & 15;
    const float* at = AT + ((size_t)(hh * 16 + f)) * 16;   // + r*1024 per iter
    const float* mt = MT + ((size_t)(hh * 16 + f)) * 16;
    size_t obase = (size_t)n * RR * DD + lane;
    for (int r = 0; r < RR; ++r) {
        const float4* a4 = (const float4*)(at + r * 1024);
        const float4* m4 = (const float4*)(mt + r * 1024);
        float ka = 0.f, va = 0.f;
#pragma unroll
        for (int j = 0; j < 4; ++j) {
            float4 a = a4[j], m = m4[j];
            ka += kd[4 * j + 0] * a.x + kd[4 * j + 1] * a.y + kd[4 * j + 2] * a.z + kd[4 * j + 3] * a.w;
            va += vd[4 * j + 0] * m.x + vd[4 * j + 1] * m.y + vd[4 * j + 2] * m.z + vd[4 * j + 3] * m.w;
        }
        k_rel[obase + (size_t)r * DD] = __float2bfloat16(ka);
        v_rel[obase + (size_t)r * DD] = __float2bfloat16(va);
    }
}

// ---- pass A (new): gather precomputed key, dot with q, logits + segment max ----
__global__ void edge_logits2_kernel(const float* __restrict__ k, const float* __restrict__ q,
                                    const __hip_bfloat16* __restrict__ k_rel,
                                    const int* __restrict__ src, const int* __restrict__ dst,
                                    const int* __restrict__ et,
                                    const float* __restrict__ pri,
                                    const float* __restrict__ nta, const float* __restrict__ nta1,
                                    const float* __restrict__ afc, const float* __restrict__ wgt,
                                    float* __restrict__ logits, unsigned* __restrict__ menc) {
    int e = (blockIdx.x * blockDim.x + threadIdx.x) >> 6;
    int lane = threadIdx.x & 63;
    if (e >= NE) return;
    int s = src[e], dd = dst[e], r = et[e];
    int hh = lane >> 4, f = lane & 15;
    float key = __bfloat162float(k_rel[((size_t)s * RR + r) * DD + lane]);
    float qv = q[(size_t)dd * DD + lane];
    float prod = qv * key;
#pragma unroll
    for (int off = 1; off < 16; off <<= 1) prod += __shfl_xor(prod, off);
    float att = prod * pri[r * HH + hh] * 0.25f;
    float kv = k[(size_t)s * DD + lane];
    float a_s = nta[src_nt(r)];
    float a_d = nta1[dst_nt(r)];
    float c = a_d * qv * afc[f] + a_s * kv * afc[16 + f];
#pragma unroll
    for (int off = 1; off < 16; off <<= 1) c += __shfl_xor(c, off);
    float na = c > 0.f ? c : 0.01f * c;
    float sw = 1.f / (1.f + expf(-wgt[0]));
    float lg = att + sw * na;
    if (f == 0) {
        logits[(size_t)e * HH + hh] = lg;
        atomicMax(&menc[((size_t)dd * RR + r) * HH + hh], enc_f(lg));
    }
}

// ---- pass B: ex = exp(logit - m); den += ex; thread per (e,h) ----
__global__ void softmax_den_kernel(const int* __restrict__ dst, const int* __restrict__ et,
                                   float* __restrict__ logits, const unsigned* __restrict__ menc,
                                   float* __restrict__ den) {
    int idx = blockIdx.x * blockDim.x + threadIdx.x;
    if (idx >= NE * HH) return;
    int e = idx >> 2, hh = idx & 3;
    int seg = (dst[e] * RR + et[e]) * HH + hh;
    float m = dec_f(menc[seg]);
    float ex = expf(logits[idx] - m);
    logits[idx] = ex;
    atomicAdd(&den[seg], ex);
}

// ---- pass C (new): gather precomputed val, t[dst] += (ex/den)*val ----
__global__ void edge_accum2_kernel(const __hip_bfloat16* __restrict__ v_rel,
                                   const int* __restrict__ src, const int* __restrict__ dst,
                                   const int* __restrict__ et,
                                   const float* __restrict__ ex, const float* __restrict__ den,
                                   float* __restrict__ tacc) {
    int e = (blockIdx.x * blockDim.x + threadIdx.x) >> 6;
    int lane = threadIdx.x & 63;
    if (e >= NE) return;
    int s = src[e], dd = dst[e], r = et[e];
    int hh = lane >> 4;
    float val = __bfloat162float(v_rel[((size_t)s * RR + r) * DD + lane]);
    int seg = (dd * RR + r) * HH + hh;
    float p = ex[(size_t)e * HH + hh] / den[seg];
    atomicAdd(&tacc[(size_t)dd * DD + lane], p * val);
}

// ---- old pass A (fallback): full per-edge matvec ----
__global__ void edge_logits_kernel(const float* __restrict__ k, const float* __restrict__ q,
                                   const int* __restrict__ src, const int* __restrict__ dst,
                                   const int* __restrict__ et,
                                   const float* __restrict__ relA, const float* __restrict__ pri,
                                   const float* __restrict__ nta, const float* __restrict__ nta1,
                                   const float* __restrict__ afc, const float* __restrict__ wgt,
                                   float* __restrict__ logits, unsigned* __restrict__ menc) {
    int e = (blockIdx.x * blockDim.x + threadIdx.x) >> 6;
    int lane = threadIdx.x & 63;
    if (e >= NE) return;
    int s = src[e], dd = dst[e], r = et[e];
    int hh = lane >> 4, f = lane & 15;
    float kv = k[(size_t)s * DD + lane];
    float qv = q[(size_t)dd * DD + lane];
    const float* A = relA + ((size_t)r * HH + hh) * DKK * DKK;
    int base = lane & 48;
    float key = 0.f;
#pragma unroll
    for (int d = 0; d < 16; ++d) {
        key += __shfl(kv, base + d) * A[d * DKK + f];
    }
    float prod = qv * key;
#pragma unroll
    for (int off = 1; off < 16; off <<= 1) prod += __shfl_xor(prod, off);
    float att = prod * pri[r * HH + hh] * 0.25f;
    float a_s = nta[src_nt(r)];
    float a_d = nta1[dst_nt(r)];
    float c = a_d * qv * afc[f] + a_s * kv * afc[16 + f];
#pragma unroll
    for (int off = 1; off < 16; off <<= 1) c += __shfl_xor(c, off);
    float na = c > 0.f ? c : 0.01f * c;
    float sw = 1.f / (1.f + expf(-wgt[0]));
    float lg = att + sw * na;
    if (f == 0) {
        logits[(size_t)e * HH + hh] = lg;
        atomicMax(&menc[((size_t)dd * RR + r) * HH + hh], enc_f(lg));
    }
}

// ---- old pass C (fallback) ----
__global__ void edge_accum_kernel(const float* __restrict__ v, const int* __restrict__ src,
                                  const int* __restrict__ dst, const int* __restrict__ et,
                                  const float* __restrict__ relM, const float* __restrict__ ex,
                                  const float* __restrict__ den, float* __restrict__ tacc) {
    int e = (blockIdx.x * blockDim.x + threadIdx.x) >> 6;
    int lane = threadIdx.x & 63;
    if (e >= NE) return;
    int s = src[e], dd = dst[e], r = et[e];
    int hh = lane >> 4, f = lane & 15;
    float vv = v[(size_t)s * DD + lane];
    const float* M = relM + ((size_t)r * HH + hh) * DKK * DKK;
    int base = lane & 48;
    float val = 0.f;
#pragma unroll
    for (int d = 0; d < 16; ++d) {
        val += __shfl(vv, base + d) * M[d * DKK + f];
    }
    int seg = (dd * RR + r) * HH + hh;
    float p = ex[(size_t)e * HH + hh] / den[seg];
    atomicAdd(&tacc[(size_t)dd * DD + lane], p * val);
}

// ---- node finalize: mean over present etypes, Wa, skip, layernorm ----
__global__ void node_out_kernel(const float* __restrict__ x_in, const float* __restrict__ tacc,
                                const float* __restrict__ den, const int* __restrict__ ntype,
                                const float* __restrict__ Wa, const float* __restrict__ ba,
                                const float* __restrict__ skipp,
                                const float* __restrict__ ln_g, const float* __restrict__ ln_b,
                                float* __restrict__ x_out) {
    int n = (blockIdx.x * blockDim.x + threadIdx.x) >> 6;
    int lane = threadIdx.x & 63;
    if (n >= NN) return;
    int t = ntype[n];
    int pres = 0;
    if (lane < RR) pres = (den[((size_t)n * RR + lane) * HH] > 0.f) ? 1 : 0;
    unsigned long long mask = __ballot(pres != 0);
    float cnt = (float)__popcll(mask);
    float divisor = fmaxf(cnt, 1.0f);
    float tv = tacc[(size_t)n * DD + lane] / divisor;
    const float* Wt = Wa + (size_t)t * DD * DD;
    float acc = ba[t * DD + lane];
#pragma unroll
    for (int d = 0; d < 64; ++d) {
        acc += __shfl(tv, d) * Wt[d * DD + lane];
    }
    float alpha = 1.f / (1.f + expf(-skipp[t]));
    float out = acc * alpha + x_in[(size_t)n * DD + lane] * (1.f - alpha);
    float s = out;
#pragma unroll
    for (int off = 1; off < 64; off <<= 1) s += __shfl_xor(s, off);
    float mu = s * (1.f / 64.f);
    float d0 = out - mu;
    float s2 = d0 * d0;
#pragma unroll
    for (int off = 1; off < 64; off <<= 1) s2 += __shfl_xor(s2, off);
    float var = s2 * (1.f / 64.f);
    float xn = d0 * rsqrtf(var + 1e-5f);
    x_out[(size_t)n * DD + lane] = xn * ln_g[t * DD + lane] + ln_b[t * DD + lane];
}

extern "C" void kernel_launch(void* const* d_in, const int* in_sizes, int n_in,
                              void* d_out, int out_size, void* d_ws, size_t ws_size,
                              hipStream_t stream) {
    const float* h       = (const float*)d_in[0];
    const int*   src     = (const int*)d_in[1];
    const int*   dst     = (const int*)d_in[2];
    const int*   etype   = (const int*)d_in[3];
    const int*   ntype   = (const int*)d_in[4];
    const float* adapt_W = (const float*)d_in[5];
    const float* adapt_b = (const float*)d_in[6];
    const float* Wk      = (const float*)d_in[7];
    const float* bk      = (const float*)d_in[8];
    const float* Wq      = (const float*)d_in[9];
    const float* bq      = (const float*)d_in[10];
    const float* Wv      = (const float*)d_in[11];
    const float* bv      = (const float*)d_in[12];
    const float* Wa      = (const float*)d_in[13];
    const float* ba      = (const float*)d_in[14];
    const float* ln_g    = (const float*)d_in[15];
    const float* ln_b    = (const float*)d_in[16];
    const float* rel_att = (const float*)d_in[17];
    const float* rel_msg = (const float*)d_in[18];
    const float* rel_pri = (const float*)d_in[19];
    const float* nta     = (const float*)d_in[20];
    const float* nta1    = (const float*)d_in[21];
    const float* skipp   = (const float*)d_in[22];
    const float* wgt     = (const float*)d_in[23];
    const float* afc_w   = (const float*)d_in[24];

    float* ws = (float*)d_ws;
    float* x0     = ws;                          // N*64
    float* x1     = x0 + (size_t)NN * DD;
    float* kb     = x1 + (size_t)NN * DD;
    float* qb     = kb + (size_t)NN * DD;
    float* vb     = qb + (size_t)NN * DD;
    float* tb     = vb + (size_t)NN * DD;
    float* logits = tb + (size_t)NN * DD;        // E*4
    float* den    = logits + (size_t)NE * HH;    // N*R*4
    unsigned* menc = (unsigned*)(den + (size_t)NN * RR * HH);  // N*R*4
    float* AT     = (float*)(menc + (size_t)NN * RR * HH);     // L*R*H*256
    float* MT     = AT + (size_t)LL * RR * HH * 256;
    __hip_bfloat16* k_rel = (__hip_bfloat16*)(MT + (size_t)LL * RR * HH * 256); // N*R*64 bf16
    __hip_bfloat16* v_rel = k_rel + (size_t)NN * RR * DD;

    size_t need_new = ((size_t)(6 * NN * DD + NE * HH + 2 * NN * RR * HH
                                + 2 * LL * RR * HH * 256)) * 4
                      + (size_t)2 * NN * RR * DD * 2;
    bool fast = ws_size >= need_new;

    const int NODE_BLOCKS = NN / 4;          // 5000
    const int EDGE_BLOCKS = NE / 4;          // 150000
    const int EH_BLOCKS   = (NE * HH) / 256; // 9375

    adapt_kernel<<<NODE_BLOCKS, 256, 0, stream>>>(h, ntype, adapt_W, adapt_b, x0);

    if (fast) {
        transpose_rel_kernel<<<(LL * RR * HH * 256) / 256, 256, 0, stream>>>(rel_att, rel_msg, AT, MT);
    }

    float* xin = x0;
    for (int l = 0; l < LL; ++l) {
        hipMemsetAsync(menc, 0, (size_t)NN * RR * HH * 4, stream);
        hipMemsetAsync(den, 0, (size_t)NN * RR * HH * 4, stream);
        hipMemsetAsync(tb, 0, (size_t)NN * DD * 4, stream);

        kqv_kernel<<<NODE_BLOCKS, 256, 0, stream>>>(
            xin, ntype,
            Wk + (size_t)l * TT * DD * DD, bk + (size_t)l * TT * DD,
            Wq + (size_t)l * TT * DD * DD, bq + (size_t)l * TT * DD,
            Wv + (size_t)l * TT * DD * DD, bv + (size_t)l * TT * DD,
            kb, qb, vb);

        if (fast) {
            relpre_kernel<<<NODE_BLOCKS, 256, 0, stream>>>(
                kb, vb,
                AT + (size_t)l * RR * HH * 256, MT + (size_t)l * RR * HH * 256,
                k_rel, v_rel);

            edge_logits2_kernel<<<EDGE_BLOCKS, 256, 0, stream>>>(
                kb, qb, k_rel, src, dst, etype,
                rel_pri + (size_t)l * RR * HH,
                nta + (size_t)l * TT, nta1 + (size_t)l * TT,
                afc_w + (size_t)l * 2 * DKK, wgt + l,
                logits, menc);

            softmax_den_kernel<<<EH_BLOCKS, 256, 0, stream>>>(dst, etype, logits, menc, den);

            edge_accum2_kernel<<<EDGE_BLOCKS, 256, 0, stream>>>(
                v_rel, src, dst, etype, logits, den, tb);
        } else {
            edge_logits_kernel<<<EDGE_BLOCKS, 256, 0, stream>>>(
                kb, qb, src, dst, etype,
                rel_att + (size_t)l * RR * HH * DKK * DKK,
                rel_pri + (size_t)l * RR * HH,
                nta + (size_t)l * TT, nta1 + (size_t)l * TT,
                afc_w + (size_t)l * 2 * DKK, wgt + l,
                logits, menc);

            softmax_den_kernel<<<EH_BLOCKS, 256, 0, stream>>>(dst, etype, logits, menc, den);

            edge_accum_kernel<<<EDGE_BLOCKS, 256, 0, stream>>>(
                vb, src, dst, etype,
                rel_msg + (size_t)l * RR * HH * DKK * DKK,
                logits, den, tb);
        }

        float* xout = (l == LL - 1) ? (float*)d_out : ((xin == x0) ? x1 : x0);
        node_out_kernel<<<NODE_BLOCKS, 256, 0, stream>>>(
            xin, tb, den, ntype,
            Wa + (size_t)l * TT * DD * DD, ba + (size_t)l * TT * DD,
            skipp + (size_t)l * TT,
            ln_g + (size_t)l * TT * DD, ln_b + (size_t)l * TT * DD,
            xout);
        xin = xout;
    }
}

// Round 3
// 1889.765 us; speedup vs baseline: 1.7107x; 1.7107x over previous
//
#include <hip/hip_runtime.h>
#include <hip/hip_bf16.h>

#define NN 20000
#define NE 600000
#define DIN 128
#define DD 64
#define HH 4
#define DKK 16
#define LL 4
#define TT 3
#define RR 32
#define CHUNK 50   // nodes per wave in relpre2 (20000 = 400*50)

__device__ __forceinline__ int src_nt(int e) { return e <= 9 ? 0 : (e <= 21 ? 1 : 2); }
__device__ __forceinline__ int dst_nt(int e) {
    if (e <= 2 || (e >= 10 && e <= 13) || (e >= 22 && e <= 24)) return 0;
    if ((e >= 3 && e <= 6) || (e >= 14 && e <= 17) || (e >= 25 && e <= 28)) return 1;
    return 2;
}
__device__ __forceinline__ float bf_lo(unsigned u) { return __uint_as_float(u << 16); }
__device__ __forceinline__ float bf_hi(unsigned u) { return __uint_as_float(u & 0xffff0000u); }

// ---- x = tanh(h @ adapt_W[ntype] + adapt_b[ntype]); wave per node ----
__global__ void adapt_kernel(const float* __restrict__ h, const int* __restrict__ ntype,
                             const float* __restrict__ W, const float* __restrict__ b,
                             float* __restrict__ x) {
    int wid = (blockIdx.x * blockDim.x + threadIdx.x) >> 6;
    int lane = threadIdx.x & 63;
    if (wid >= NN) return;
    int t = ntype[wid];
    const float* Wt = W + (size_t)t * DIN * DD;
    float h0 = h[(size_t)wid * DIN + lane];
    float h1 = h[(size_t)wid * DIN + 64 + lane];
    float acc = b[t * DD + lane];
#pragma unroll
    for (int d = 0; d < 64; ++d) acc += __shfl(h0, d) * Wt[d * DD + lane];
#pragma unroll
    for (int d = 0; d < 64; ++d) acc += __shfl(h1, d) * Wt[(64 + d) * DD + lane];
    x[(size_t)wid * DD + lane] = tanhf(acc);
}

// ---- transpose rel matrices: [l][r][h][d][f] -> [l][r][h][f][d] ----
__global__ void transpose_rel_kernel(const float* __restrict__ relA, const float* __restrict__ relM,
                                     float* __restrict__ AT, float* __restrict__ MT) {
    int idx = blockIdx.x * blockDim.x + threadIdx.x;
    if (idx >= LL * RR * HH * 256) return;
    int sidx = (idx & ~255) + ((idx & 15) << 4) + ((idx >> 4) & 15);
    AT[idx] = relA[sidx];
    MT[idx] = relM[sidx];
}

// ---- CSR build: count, scan, fill ----
__global__ void csr_count_kernel(const int* __restrict__ dst, int* __restrict__ cnt) {
    int e = blockIdx.x * blockDim.x + threadIdx.x;
    if (e < NE) atomicAdd(&cnt[dst[e]], 1);
}

__global__ void csr_scan_kernel(const int* __restrict__ cnt, int* __restrict__ rowptr,
                                int* __restrict__ cursor) {
    __shared__ int wsum[16];
    __shared__ int s_carry;
    int tid = threadIdx.x;            // blockDim = 1024
    int lane = tid & 63, wid = tid >> 6;
    if (tid == 0) s_carry = 0;
    __syncthreads();
    for (int base = 0; base < NN; base += 1024) {
        int i = base + tid;
        int v = (i < NN) ? cnt[i] : 0;
        int x = v;
#pragma unroll
        for (int off = 1; off < 64; off <<= 1) {
            int y = __shfl_up(x, off);
            if (lane >= off) x += y;
        }
        if (lane == 63) wsum[wid] = x;
        __syncthreads();
        if (wid == 0 && lane < 16) {
            int w = wsum[lane];
#pragma unroll
            for (int off = 1; off < 16; off <<= 1) {
                int y = __shfl_up(w, off);
                if (lane >= off) w += y;
            }
            wsum[lane] = w;
        }
        __syncthreads();
        int woff = (wid > 0) ? wsum[wid - 1] : 0;
        int carry = s_carry;
        int excl = carry + woff + x - v;
        if (i < NN) { rowptr[i] = excl; cursor[i] = excl; }
        __syncthreads();
        if (tid == 1023) s_carry = carry + wsum[15];
        __syncthreads();
    }
    if (tid == 0) rowptr[NN] = NE;
}

__global__ void csr_fill_kernel(const int* __restrict__ dst, int* __restrict__ cursor,
                                int* __restrict__ eids) {
    int e = blockIdx.x * blockDim.x + threadIdx.x;
    if (e >= NE) return;
    int p = atomicAdd(&cursor[dst[e]], 1);
    eids[p] = e;
}

// ---- k,q,v + na_q/na_k; wave per node ----
__global__ void kqv_kernel(const float* __restrict__ x, const int* __restrict__ ntype,
                           const float* __restrict__ Wk, const float* __restrict__ bk,
                           const float* __restrict__ Wq, const float* __restrict__ bq,
                           const float* __restrict__ Wv, const float* __restrict__ bv,
                           const float* __restrict__ afc,
                           float* __restrict__ k, float* __restrict__ q, float* __restrict__ v,
                           float* __restrict__ na_q, float* __restrict__ na_k) {
    int wid = (blockIdx.x * blockDim.x + threadIdx.x) >> 6;
    int lane = threadIdx.x & 63;
    if (wid >= NN) return;
    int t = ntype[wid];
    const float* Wkt = Wk + (size_t)t * DD * DD;
    const float* Wqt = Wq + (size_t)t * DD * DD;
    const float* Wvt = Wv + (size_t)t * DD * DD;
    float xv = x[(size_t)wid * DD + lane];
    float ak = bk[t * DD + lane];
    float aq = bq[t * DD + lane];
    float av = bv[t * DD + lane];
#pragma unroll
    for (int d = 0; d < 64; ++d) {
        float xd = __shfl(xv, d);
        ak += xd * Wkt[d * DD + lane];
        aq += xd * Wqt[d * DD + lane];
        av += xd * Wvt[d * DD + lane];
    }
    k[(size_t)wid * DD + lane] = ak;
    q[(size_t)wid * DD + lane] = aq;
    v[(size_t)wid * DD + lane] = av;
    int f = lane & 15;
    float cq = aq * afc[f];
    float ck = ak * afc[16 + f];
#pragma unroll
    for (int off = 1; off < 16; off <<= 1) {
        cq += __shfl_xor(cq, off);
        ck += __shfl_xor(ck, off);
    }
    if (f == 0) {
        na_q[wid * HH + (lane >> 4)] = cq;
        na_k[wid * HH + (lane >> 4)] = ck;
    }
}

// ---- relpre v2: wave owns one r (matrices in regs), streams CHUNK nodes ----
__global__ void relpre2_kernel(const float* __restrict__ k, const float* __restrict__ v,
                               const float* __restrict__ AT, const float* __restrict__ MT,
                               __hip_bfloat16* __restrict__ k_rel, __hip_bfloat16* __restrict__ v_rel) {
    int gw = (blockIdx.x * blockDim.x + threadIdx.x) >> 6;
    int lane = threadIdx.x & 63;
    int r = gw & 31;
    int n0 = (gw >> 5) * CHUNK;
    if (n0 >= NN) return;
    const float4* a4 = (const float4*)(AT + ((size_t)r * 64 + lane) * 16);
    const float4* m4 = (const float4*)(MT + ((size_t)r * 64 + lane) * 16);
    float a[16], m[16];
#pragma unroll
    for (int j = 0; j < 4; ++j) {
        float4 ta = a4[j], tm = m4[j];
        a[4 * j + 0] = ta.x; a[4 * j + 1] = ta.y; a[4 * j + 2] = ta.z; a[4 * j + 3] = ta.w;
        m[4 * j + 0] = tm.x; m[4 * j + 1] = tm.y; m[4 * j + 2] = tm.z; m[4 * j + 3] = tm.w;
    }
    int base = lane & 48;
    for (int n = n0; n < n0 + CHUNK; ++n) {
        float kv = k[(size_t)n * DD + lane];
        float vv = v[(size_t)n * DD + lane];
        float ka = 0.f, va = 0.f;
#pragma unroll
        for (int d = 0; d < 16; ++d) {
            float kd = __shfl(kv, base + d);
            float vd = __shfl(vv, base + d);
            ka += kd * a[d];
            va += vd * m[d];
        }
        size_t o = ((size_t)n * RR + r) * DD + lane;
        k_rel[o] = __float2bfloat16(ka);
        v_rel[o] = __float2bfloat16(va);
    }
}

// ---- edge pass: thread per (e,h); logits -> ex (no max, values are O(1)) + den ----
__global__ void edge_logits3_kernel(const float* __restrict__ q,
                                    const __hip_bfloat16* __restrict__ k_rel,
                                    const int* __restrict__ src, const int* __restrict__ dst,
                                    const int* __restrict__ et,
                                    const float* __restrict__ pri,
                                    const float* __restrict__ nta, const float* __restrict__ nta1,
                                    const float* __restrict__ na_q, const float* __restrict__ na_k,
                                    const float* __restrict__ afc_unused, const float* __restrict__ wgt,
                                    float* __restrict__ ex_out, float* __restrict__ den) {
    int idx = blockIdx.x * blockDim.x + threadIdx.x;
    if (idx >= NE * HH) return;
    int e = idx >> 2, hh = idx & 3;
    int s = src[e], dd = dst[e], r = et[e];
    const uint4* kr = (const uint4*)(k_rel + ((size_t)s * RR + r) * DD + hh * 16);
    uint4 p0 = kr[0], p1 = kr[1];
    const float4* qp = (const float4*)(q + (size_t)dd * DD + hh * 16);
    float4 q0 = qp[0], q1 = qp[1], q2 = qp[2], q3 = qp[3];
    float att = q0.x * bf_lo(p0.x) + q0.y * bf_hi(p0.x)
              + q0.z * bf_lo(p0.y) + q0.w * bf_hi(p0.y)
              + q1.x * bf_lo(p0.z) + q1.y * bf_hi(p0.z)
              + q1.z * bf_lo(p0.w) + q1.w * bf_hi(p0.w)
              + q2.x * bf_lo(p1.x) + q2.y * bf_hi(p1.x)
              + q2.z * bf_lo(p1.y) + q2.w * bf_hi(p1.y)
              + q3.x * bf_lo(p1.z) + q3.y * bf_hi(p1.z)
              + q3.z * bf_lo(p1.w) + q3.w * bf_hi(p1.w);
    att = att * pri[r * HH + hh] * 0.25f;
    float c = nta1[dst_nt(r)] * na_q[dd * HH + hh] + nta[src_nt(r)] * na_k[s * HH + hh];
    float na = c > 0.f ? c : 0.01f * c;
    float sw = 1.f / (1.f + expf(-wgt[0]));
    float exv = expf(att + sw * na);
    ex_out[idx] = exv;
    atomicAdd(&den[((size_t)dd * RR + r) * HH + hh], exv);
}

// ---- accumulation: wave per dst via CSR, no atomics ----
__global__ void accum_csr_kernel(const __hip_bfloat16* __restrict__ v_rel,
                                 const int* __restrict__ src, const int* __restrict__ et,
                                 const int* __restrict__ rowptr, const int* __restrict__ eids,
                                 const float* __restrict__ ex, const float* __restrict__ den,
                                 float* __restrict__ tacc) {
    int n = (blockIdx.x * blockDim.x + threadIdx.x) >> 6;
    int lane = threadIdx.x & 63;
    if (n >= NN) return;
    int beg = rowptr[n], end = rowptr[n + 1];
    int hh = lane >> 4;
    float acc = 0.f;
    for (int j = beg; j < end; ++j) {
        int e = eids[j];
        int s = src[e], r = et[e];
        float p = ex[(size_t)e * HH + hh];
        float dn = den[((size_t)n * RR + r) * HH + hh];
        float val = __bfloat162float(v_rel[((size_t)s * RR + r) * DD + lane]);
        acc += p * __builtin_amdgcn_rcpf(dn) * val;
    }
    tacc[(size_t)n * DD + lane] = acc;
}

// ---- node finalize ----
__global__ void node_out_kernel(const float* __restrict__ x_in, const float* __restrict__ tacc,
                                const float* __restrict__ den, const int* __restrict__ ntype,
                                const float* __restrict__ Wa, const float* __restrict__ ba,
                                const float* __restrict__ skipp,
                                const float* __restrict__ ln_g, const float* __restrict__ ln_b,
                                float* __restrict__ x_out) {
    int n = (blockIdx.x * blockDim.x + threadIdx.x) >> 6;
    int lane = threadIdx.x & 63;
    if (n >= NN) return;
    int t = ntype[n];
    int pres = 0;
    if (lane < RR) pres = (den[((size_t)n * RR + lane) * HH] > 0.f) ? 1 : 0;
    unsigned long long mask = __ballot(pres != 0);
    float cnt = (float)__popcll(mask);
    float divisor = fmaxf(cnt, 1.0f);
    float tv = tacc[(size_t)n * DD + lane] / divisor;
    const float* Wt = Wa + (size_t)t * DD * DD;
    float acc = ba[t * DD + lane];
#pragma unroll
    for (int d = 0; d < 64; ++d) acc += __shfl(tv, d) * Wt[d * DD + lane];
    float alpha = 1.f / (1.f + expf(-skipp[t]));
    float out = acc * alpha + x_in[(size_t)n * DD + lane] * (1.f - alpha);
    float s = out;
#pragma unroll
    for (int off = 1; off < 64; off <<= 1) s += __shfl_xor(s, off);
    float mu = s * (1.f / 64.f);
    float d0 = out - mu;
    float s2 = d0 * d0;
#pragma unroll
    for (int off = 1; off < 64; off <<= 1) s2 += __shfl_xor(s2, off);
    float var = s2 * (1.f / 64.f);
    float xn = d0 * rsqrtf(var + 1e-5f);
    x_out[(size_t)n * DD + lane] = xn * ln_g[t * DD + lane] + ln_b[t * DD + lane];
}

extern "C" void kernel_launch(void* const* d_in, const int* in_sizes, int n_in,
                              void* d_out, int out_size, void* d_ws, size_t ws_size,
                              hipStream_t stream) {
    const float* h       = (const float*)d_in[0];
    const int*   src     = (const int*)d_in[1];
    const int*   dst     = (const int*)d_in[2];
    const int*   etype   = (const int*)d_in[3];
    const int*   ntype   = (const int*)d_in[4];
    const float* adapt_W = (const float*)d_in[5];
    const float* adapt_b = (const float*)d_in[6];
    const float* Wk      = (const float*)d_in[7];
    const float* bk      = (const float*)d_in[8];
    const float* Wq      = (const float*)d_in[9];
    const float* bq      = (const float*)d_in[10];
    const float* Wv      = (const float*)d_in[11];
    const float* bv      = (const float*)d_in[12];
    const float* Wa      = (const float*)d_in[13];
    const float* ba      = (const float*)d_in[14];
    const float* ln_g    = (const float*)d_in[15];
    const float* ln_b    = (const float*)d_in[16];
    const float* rel_att = (const float*)d_in[17];
    const float* rel_msg = (const float*)d_in[18];
    const float* rel_pri = (const float*)d_in[19];
    const float* nta     = (const float*)d_in[20];
    const float* nta1    = (const float*)d_in[21];
    const float* skipp   = (const float*)d_in[22];
    const float* wgt     = (const float*)d_in[23];
    const float* afc_w   = (const float*)d_in[24];

    // 64B-aligned bump allocator over d_ws
    char* cur = (char*)d_ws;
    auto alloc = [&](size_t bytes) {
        char* p = cur;
        cur += (bytes + 63) & ~(size_t)63;
        return (void*)p;
    };
    float* x0     = (float*)alloc((size_t)NN * DD * 4);
    float* x1     = (float*)alloc((size_t)NN * DD * 4);
    float* kb     = (float*)alloc((size_t)NN * DD * 4);
    float* qb     = (float*)alloc((size_t)NN * DD * 4);
    float* vb     = (float*)alloc((size_t)NN * DD * 4);
    float* tb     = (float*)alloc((size_t)NN * DD * 4);
    float* exbuf  = (float*)alloc((size_t)NE * HH * 4);
    float* den    = (float*)alloc((size_t)NN * RR * HH * 4);
    float* AT     = (float*)alloc((size_t)LL * RR * HH * 256 * 4);
    float* MT     = (float*)alloc((size_t)LL * RR * HH * 256 * 4);
    float* na_q   = (float*)alloc((size_t)NN * HH * 4);
    float* na_k   = (float*)alloc((size_t)NN * HH * 4);
    int*   cnt    = (int*)alloc((size_t)NN * 4);
    int*   rowptr = (int*)alloc((size_t)(NN + 1) * 4);
    int*   cursor = (int*)alloc((size_t)NN * 4);
    int*   eids   = (int*)alloc((size_t)NE * 4);
    __hip_bfloat16* k_rel = (__hip_bfloat16*)alloc((size_t)NN * RR * DD * 2);
    __hip_bfloat16* v_rel = (__hip_bfloat16*)alloc((size_t)NN * RR * DD * 2);

    const int NODE_BLOCKS = NN / 4;            // 5000
    const int E_BLOCKS    = (NE + 255) / 256;  // 2344
    const int EH_BLOCKS   = (NE * HH) / 256;   // 9375
    const int RP_BLOCKS   = (32 * (NN / CHUNK)) / 4;  // 3200

    adapt_kernel<<<NODE_BLOCKS, 256, 0, stream>>>(h, ntype, adapt_W, adapt_b, x0);
    transpose_rel_kernel<<<(LL * RR * HH * 256) / 256, 256, 0, stream>>>(rel_att, rel_msg, AT, MT);

    hipMemsetAsync(cnt, 0, (size_t)NN * 4, stream);
    csr_count_kernel<<<E_BLOCKS, 256, 0, stream>>>(dst, cnt);
    csr_scan_kernel<<<1, 1024, 0, stream>>>(cnt, rowptr, cursor);
    csr_fill_kernel<<<E_BLOCKS, 256, 0, stream>>>(dst, cursor, eids);

    float* xin = x0;
    for (int l = 0; l < LL; ++l) {
        hipMemsetAsync(den, 0, (size_t)NN * RR * HH * 4, stream);

        kqv_kernel<<<NODE_BLOCKS, 256, 0, stream>>>(
            xin, ntype,
            Wk + (size_t)l * TT * DD * DD, bk + (size_t)l * TT * DD,
            Wq + (size_t)l * TT * DD * DD, bq + (size_t)l * TT * DD,
            Wv + (size_t)l * TT * DD * DD, bv + (size_t)l * TT * DD,
            afc_w + (size_t)l * 2 * DKK,
            kb, qb, vb, na_q, na_k);

        relpre2_kernel<<<RP_BLOCKS, 256, 0, stream>>>(
            kb, vb,
            AT + (size_t)l * RR * HH * 256, MT + (size_t)l * RR * HH * 256,
            k_rel, v_rel);

        edge_logits3_kernel<<<EH_BLOCKS, 256, 0, stream>>>(
            qb, k_rel, src, dst, etype,
            rel_pri + (size_t)l * RR * HH,
            nta + (size_t)l * TT, nta1 + (size_t)l * TT,
            na_q, na_k,
            afc_w + (size_t)l * 2 * DKK, wgt + l,
            exbuf, den);

        accum_csr_kernel<<<NODE_BLOCKS, 256, 0, stream>>>(
            v_rel, src, etype, rowptr, eids, exbuf, den, tb);

        float* xout = (l == LL - 1) ? (float*)d_out : ((xin == x0) ? x1 : x0);
        node_out_kernel<<<NODE_BLOCKS, 256, 0, stream>>>(
            xin, tb, den, ntype,
            Wa + (size_t)l * TT * DD * DD, ba + (size_t)l * TT * DD,
            skipp + (size_t)l * TT,
            ln_g + (size_t)l * TT * DD, ln_b + (size_t)l * TT * DD,
            xout);
        xin = xout;
    }
}

// Round 4
// 1346.749 us; speedup vs baseline: 2.4004x; 1.4032x over previous
//
#include <hip/hip_runtime.h>
#include <hip/hip_bf16.h>

#define NN 20000
#define NE 600000
#define DIN 128
#define DD 64
#define HH 4
#define DKK 16
#define LL 4
#define TT 3
#define RR 32
#define NCH 25          // N-chunks per (r,h) in relpre3; 1250 tiles = NCH*50

typedef __attribute__((ext_vector_type(8))) short bf16x8;
typedef __attribute__((ext_vector_type(4))) float f32x4;

__device__ __forceinline__ int src_nt(int e) { return e <= 9 ? 0 : (e <= 21 ? 1 : 2); }
__device__ __forceinline__ int dst_nt(int e) {
    if (e <= 2 || (e >= 10 && e <= 13) || (e >= 22 && e <= 24)) return 0;
    if ((e >= 3 && e <= 6) || (e >= 14 && e <= 17) || (e >= 25 && e <= 28)) return 1;
    return 2;
}
__device__ __forceinline__ float bf_lo(unsigned u) { return __uint_as_float(u << 16); }
__device__ __forceinline__ float bf_hi(unsigned u) { return __uint_as_float(u & 0xffff0000u); }
// round-to-nearest-even f32 -> bf16 bits
__device__ __forceinline__ ushort f2bf(float x) {
    unsigned u = __float_as_uint(x);
    return (ushort)((u + 0x7fffu + ((u >> 16) & 1u)) >> 16);
}

// ---- x = tanh(h @ adapt_W[ntype] + adapt_b[ntype]); wave per node ----
__global__ void adapt_kernel(const float* __restrict__ h, const int* __restrict__ ntype,
                             const float* __restrict__ W, const float* __restrict__ b,
                             float* __restrict__ x) {
    int wid = (blockIdx.x * blockDim.x + threadIdx.x) >> 6;
    int lane = threadIdx.x & 63;
    if (wid >= NN) return;
    int t = ntype[wid];
    const float* Wt = W + (size_t)t * DIN * DD;
    float h0 = h[(size_t)wid * DIN + lane];
    float h1 = h[(size_t)wid * DIN + 64 + lane];
    float acc = b[t * DD + lane];
#pragma unroll
    for (int d = 0; d < 64; ++d) acc += __shfl(h0, d) * Wt[d * DD + lane];
#pragma unroll
    for (int d = 0; d < 64; ++d) acc += __shfl(h1, d) * Wt[(64 + d) * DD + lane];
    x[(size_t)wid * DD + lane] = tanhf(acc);
}

// ---- CSR build: count, scan, fill ----
__global__ void csr_count_kernel(const int* __restrict__ dst, int* __restrict__ cnt) {
    int e = blockIdx.x * blockDim.x + threadIdx.x;
    if (e < NE) atomicAdd(&cnt[dst[e]], 1);
}

__global__ void csr_scan_kernel(const int* __restrict__ cnt, int* __restrict__ rowptr,
                                int* __restrict__ cursor) {
    __shared__ int wsum[16];
    __shared__ int s_carry;
    int tid = threadIdx.x;            // blockDim = 1024
    int lane = tid & 63, wid = tid >> 6;
    if (tid == 0) s_carry = 0;
    __syncthreads();
    for (int base = 0; base < NN; base += 1024) {
        int i = base + tid;
        int v = (i < NN) ? cnt[i] : 0;
        int x = v;
#pragma unroll
        for (int off = 1; off < 64; off <<= 1) {
            int y = __shfl_up(x, off);
            if (lane >= off) x += y;
        }
        if (lane == 63) wsum[wid] = x;
        __syncthreads();
        if (wid == 0 && lane < 16) {
            int w = wsum[lane];
#pragma unroll
            for (int off = 1; off < 16; off <<= 1) {
                int y = __shfl_up(w, off);
                if (lane >= off) w += y;
            }
            wsum[lane] = w;
        }
        __syncthreads();
        int woff = (wid > 0) ? wsum[wid - 1] : 0;
        int carry = s_carry;
        int excl = carry + woff + x - v;
        if (i < NN) { rowptr[i] = excl; cursor[i] = excl; }
        __syncthreads();
        if (tid == 1023) s_carry = carry + wsum[15];
        __syncthreads();
    }
    if (tid == 0) rowptr[NN] = NE;
}

__global__ void csr_fill_kernel(const int* __restrict__ dst, int* __restrict__ cursor,
                                int* __restrict__ eids) {
    int e = blockIdx.x * blockDim.x + threadIdx.x;
    if (e >= NE) return;
    int p = atomicAdd(&cursor[dst[e]], 1);
    eids[p] = e;
}

// ---- k,q,v + na_q/na_k; wave per node; k,v emitted as bf16 ----
__global__ void kqv_kernel(const float* __restrict__ x, const int* __restrict__ ntype,
                           const float* __restrict__ Wk, const float* __restrict__ bk,
                           const float* __restrict__ Wq, const float* __restrict__ bq,
                           const float* __restrict__ Wv, const float* __restrict__ bv,
                           const float* __restrict__ afc,
                           ushort* __restrict__ kbf, float* __restrict__ q, ushort* __restrict__ vbf,
                           float* __restrict__ na_q, float* __restrict__ na_k) {
    int wid = (blockIdx.x * blockDim.x + threadIdx.x) >> 6;
    int lane = threadIdx.x & 63;
    if (wid >= NN) return;
    int t = ntype[wid];
    const float* Wkt = Wk + (size_t)t * DD * DD;
    const float* Wqt = Wq + (size_t)t * DD * DD;
    const float* Wvt = Wv + (size_t)t * DD * DD;
    float xv = x[(size_t)wid * DD + lane];
    float ak = bk[t * DD + lane];
    float aq = bq[t * DD + lane];
    float av = bv[t * DD + lane];
#pragma unroll
    for (int d = 0; d < 64; ++d) {
        float xd = __shfl(xv, d);
        ak += xd * Wkt[d * DD + lane];
        aq += xd * Wqt[d * DD + lane];
        av += xd * Wvt[d * DD + lane];
    }
    kbf[(size_t)wid * DD + lane] = f2bf(ak);
    q[(size_t)wid * DD + lane] = aq;
    vbf[(size_t)wid * DD + lane] = f2bf(av);
    int f = lane & 15;
    float cq = aq * afc[f];
    float ck = ak * afc[16 + f];
#pragma unroll
    for (int off = 1; off < 16; off <<= 1) {
        cq += __shfl_xor(cq, off);
        ck += __shfl_xor(ck, off);
    }
    if (f == 0) {
        na_q[wid * HH + (lane >> 4)] = cq;
        na_k[wid * HH + (lane >> 4)] = ck;
    }
}

// ---- relpre v3: MFMA. wave owns (r,h,chunk); D[f][node] = rel^T-frag x k-frag ----
// A-operand (M=f=16, K=d zero-padded to 32): lane l, elem j -> rel[r][h][d=(l>>4)*8+j][f=l&15]
// B-operand (K=d, N=node=16): lane l, elem j -> kbf[n0+(l&15)][h*16 + (l>>4)*8 + j]
// D: col(l&15)=node offset, rows (l>>4)*4+j = f -> 4 consecutive f = one 8B store
__global__ void relpre3_kernel(const ushort* __restrict__ kbf, const ushort* __restrict__ vbf,
                               const float* __restrict__ relA, const float* __restrict__ relM,
                               ushort* __restrict__ k_rel, ushort* __restrict__ v_rel) {
    int gw = (blockIdx.x * blockDim.x + threadIdx.x) >> 6;
    int lane = threadIdx.x & 63;
    int c  = gw % NCH;
    int rh = gw / NCH;            // 0..127
    int h  = rh & 3;
    int r  = rh >> 2;
    int f  = lane & 15;
    int d0 = (lane >> 4) * 8;
    bf16x8 aK = {0, 0, 0, 0, 0, 0, 0, 0};
    bf16x8 aM = {0, 0, 0, 0, 0, 0, 0, 0};
    if (d0 < 16) {
        const float* Ab = relA + (size_t)(r * HH + h) * 256;
        const float* Mb = relM + (size_t)(r * HH + h) * 256;
#pragma unroll
        for (int j = 0; j < 8; ++j) {
            aK[j] = (short)f2bf(Ab[(d0 + j) * 16 + f]);
            aM[j] = (short)f2bf(Mb[(d0 + j) * 16 + f]);
        }
    }
    int dsafe = d0 & 15;          // lanes 32-63 duplicate lanes 0-31 (multiplied by zero A)
    int hbase = h * 16;
    int frow = (lane >> 4) * 4;
    for (int t = 0; t < 1250 / NCH; ++t) {
        int n0 = (c * (1250 / NCH) + t) * 16;
        size_t brow = (size_t)(n0 + f) * DD + hbase + dsafe;
        bf16x8 bK = *(const bf16x8*)(kbf + brow);
        bf16x8 bV = *(const bf16x8*)(vbf + brow);
        f32x4 ck = {0.f, 0.f, 0.f, 0.f};
        f32x4 cv = {0.f, 0.f, 0.f, 0.f};
        ck = __builtin_amdgcn_mfma_f32_16x16x32_bf16(aK, bK, ck, 0, 0, 0);
        cv = __builtin_amdgcn_mfma_f32_16x16x32_bf16(aM, bV, cv, 0, 0, 0);
        size_t obase = ((size_t)(n0 + f) * RR + r) * DD + hbase + frow;
        ushort4 ok, ov;
        ok.x = f2bf(ck[0]); ok.y = f2bf(ck[1]); ok.z = f2bf(ck[2]); ok.w = f2bf(ck[3]);
        ov.x = f2bf(cv[0]); ov.y = f2bf(cv[1]); ov.z = f2bf(cv[2]); ov.w = f2bf(cv[3]);
        *(ushort4*)(k_rel + obase) = ok;
        *(ushort4*)(v_rel + obase) = ov;
    }
}

// ---- edge pass: thread per (e,h); ex = exp(logit) (no max; logits O(1)) + den ----
__global__ void edge_logits3_kernel(const float* __restrict__ q,
                                    const ushort* __restrict__ k_rel,
                                    const int* __restrict__ src, const int* __restrict__ dst,
                                    const int* __restrict__ et,
                                    const float* __restrict__ pri,
                                    const float* __restrict__ nta, const float* __restrict__ nta1,
                                    const float* __restrict__ na_q, const float* __restrict__ na_k,
                                    const float* __restrict__ wgt,
                                    float* __restrict__ ex_out, float* __restrict__ den) {
    int idx = blockIdx.x * blockDim.x + threadIdx.x;
    if (idx >= NE * HH) return;
    int e = idx >> 2, hh = idx & 3;
    int s = src[e], dd = dst[e], r = et[e];
    const uint4* kr = (const uint4*)(k_rel + ((size_t)s * RR + r) * DD + hh * 16);
    uint4 p0 = kr[0], p1 = kr[1];
    const float4* qp = (const float4*)(q + (size_t)dd * DD + hh * 16);
    float4 q0 = qp[0], q1 = qp[1], q2 = qp[2], q3 = qp[3];
    float att = q0.x * bf_lo(p0.x) + q0.y * bf_hi(p0.x)
              + q0.z * bf_lo(p0.y) + q0.w * bf_hi(p0.y)
              + q1.x * bf_lo(p0.z) + q1.y * bf_hi(p0.z)
              + q1.z * bf_lo(p0.w) + q1.w * bf_hi(p0.w)
              + q2.x * bf_lo(p1.x) + q2.y * bf_hi(p1.x)
              + q2.z * bf_lo(p1.y) + q2.w * bf_hi(p1.y)
              + q3.x * bf_lo(p1.z) + q3.y * bf_hi(p1.z)
              + q3.z * bf_lo(p1.w) + q3.w * bf_hi(p1.w);
    att = att * pri[r * HH + hh] * 0.25f;
    float c = nta1[dst_nt(r)] * na_q[dd * HH + hh] + nta[src_nt(r)] * na_k[s * HH + hh];
    float na = c > 0.f ? c : 0.01f * c;
    float sw = 1.f / (1.f + expf(-wgt[0]));
    float exv = expf(att + sw * na);
    ex_out[idx] = exv;
    atomicAdd(&den[((size_t)dd * RR + r) * HH + hh], exv);
}

// ---- accumulation: wave per dst via CSR, no atomics ----
__global__ void accum_csr_kernel(const ushort* __restrict__ v_rel,
                                 const int* __restrict__ src, const int* __restrict__ et,
                                 const int* __restrict__ rowptr, const int* __restrict__ eids,
                                 const float* __restrict__ ex, const float* __restrict__ den,
                                 float* __restrict__ tacc) {
    int n = (blockIdx.x * blockDim.x + threadIdx.x) >> 6;
    int lane = threadIdx.x & 63;
    if (n >= NN) return;
    int beg = rowptr[n], end = rowptr[n + 1];
    int hh = lane >> 4;
    float acc = 0.f;
    for (int j = beg; j < end; ++j) {
        int e = eids[j];
        int s = src[e], r = et[e];
        float p = ex[(size_t)e * HH + hh];
        float dn = den[((size_t)n * RR + r) * HH + hh];
        float val = bf_lo((unsigned)v_rel[((size_t)s * RR + r) * DD + lane]);
        acc += p * __builtin_amdgcn_rcpf(dn) * val;
    }
    tacc[(size_t)n * DD + lane] = acc;
}

// ---- node finalize ----
__global__ void node_out_kernel(const float* __restrict__ x_in, const float* __restrict__ tacc,
                                const float* __restrict__ den, const int* __restrict__ ntype,
                                const float* __restrict__ Wa, const float* __restrict__ ba,
                                const float* __restrict__ skipp,
                                const float* __restrict__ ln_g, const float* __restrict__ ln_b,
                                float* __restrict__ x_out) {
    int n = (blockIdx.x * blockDim.x + threadIdx.x) >> 6;
    int lane = threadIdx.x & 63;
    if (n >= NN) return;
    int t = ntype[n];
    int pres = 0;
    if (lane < RR) pres = (den[((size_t)n * RR + lane) * HH] > 0.f) ? 1 : 0;
    unsigned long long mask = __ballot(pres != 0);
    float cnt = (float)__popcll(mask);
    float divisor = fmaxf(cnt, 1.0f);
    float tv = tacc[(size_t)n * DD + lane] / divisor;
    const float* Wt = Wa + (size_t)t * DD * DD;
    float acc = ba[t * DD + lane];
#pragma unroll
    for (int d = 0; d < 64; ++d) acc += __shfl(tv, d) * Wt[d * DD + lane];
    float alpha = 1.f / (1.f + expf(-skipp[t]));
    float out = acc * alpha + x_in[(size_t)n * DD + lane] * (1.f - alpha);
    float s = out;
#pragma unroll
    for (int off = 1; off < 64; off <<= 1) s += __shfl_xor(s, off);
    float mu = s * (1.f / 64.f);
    float d0 = out - mu;
    float s2 = d0 * d0;
#pragma unroll
    for (int off = 1; off < 64; off <<= 1) s2 += __shfl_xor(s2, off);
    float var = s2 * (1.f / 64.f);
    float xn = d0 * rsqrtf(var + 1e-5f);
    x_out[(size_t)n * DD + lane] = xn * ln_g[t * DD + lane] + ln_b[t * DD + lane];
}

extern "C" void kernel_launch(void* const* d_in, const int* in_sizes, int n_in,
                              void* d_out, int out_size, void* d_ws, size_t ws_size,
                              hipStream_t stream) {
    const float* h       = (const float*)d_in[0];
    const int*   src     = (const int*)d_in[1];
    const int*   dst     = (const int*)d_in[2];
    const int*   etype   = (const int*)d_in[3];
    const int*   ntype   = (const int*)d_in[4];
    const float* adapt_W = (const float*)d_in[5];
    const float* adapt_b = (const float*)d_in[6];
    const float* Wk      = (const float*)d_in[7];
    const float* bk      = (const float*)d_in[8];
    const float* Wq      = (const float*)d_in[9];
    const float* bq      = (const float*)d_in[10];
    const float* Wv      = (const float*)d_in[11];
    const float* bv      = (const float*)d_in[12];
    const float* Wa      = (const float*)d_in[13];
    const float* ba      = (const float*)d_in[14];
    const float* ln_g    = (const float*)d_in[15];
    const float* ln_b    = (const float*)d_in[16];
    const float* rel_att = (const float*)d_in[17];
    const float* rel_msg = (const float*)d_in[18];
    const float* rel_pri = (const float*)d_in[19];
    const float* nta     = (const float*)d_in[20];
    const float* nta1    = (const float*)d_in[21];
    const float* skipp   = (const float*)d_in[22];
    const float* wgt     = (const float*)d_in[23];
    const float* afc_w   = (const float*)d_in[24];

    char* cur = (char*)d_ws;
    auto alloc = [&](size_t bytes) {
        char* p = cur;
        cur += (bytes + 63) & ~(size_t)63;
        return (void*)p;
    };
    float* x0     = (float*)alloc((size_t)NN * DD * 4);
    float* x1     = (float*)alloc((size_t)NN * DD * 4);
    ushort* kbf   = (ushort*)alloc((size_t)NN * DD * 2);
    float* qb     = (float*)alloc((size_t)NN * DD * 4);
    ushort* vbf   = (ushort*)alloc((size_t)NN * DD * 2);
    float* tb     = (float*)alloc((size_t)NN * DD * 4);
    float* exbuf  = (float*)alloc((size_t)NE * HH * 4);
    float* den    = (float*)alloc((size_t)NN * RR * HH * 4);
    float* na_q   = (float*)alloc((size_t)NN * HH * 4);
    float* na_k   = (float*)alloc((size_t)NN * HH * 4);
    int*   cnt    = (int*)alloc((size_t)NN * 4);
    int*   rowptr = (int*)alloc((size_t)(NN + 1) * 4);
    int*   cursor = (int*)alloc((size_t)NN * 4);
    int*   eids   = (int*)alloc((size_t)NE * 4);
    ushort* k_rel = (ushort*)alloc((size_t)NN * RR * DD * 2);
    ushort* v_rel = (ushort*)alloc((size_t)NN * RR * DD * 2);

    const int NODE_BLOCKS = NN / 4;            // 5000
    const int E_BLOCKS    = (NE + 255) / 256;  // 2344
    const int EH_BLOCKS   = (NE * HH) / 256;   // 9375
    const int RP3_BLOCKS  = (RR * HH * NCH) / 4;  // 800 (3200 waves)

    adapt_kernel<<<NODE_BLOCKS, 256, 0, stream>>>(h, ntype, adapt_W, adapt_b, x0);

    hipMemsetAsync(cnt, 0, (size_t)NN * 4, stream);
    csr_count_kernel<<<E_BLOCKS, 256, 0, stream>>>(dst, cnt);
    csr_scan_kernel<<<1, 1024, 0, stream>>>(cnt, rowptr, cursor);
    csr_fill_kernel<<<E_BLOCKS, 256, 0, stream>>>(dst, cursor, eids);

    float* xin = x0;
    for (int l = 0; l < LL; ++l) {
        hipMemsetAsync(den, 0, (size_t)NN * RR * HH * 4, stream);

        kqv_kernel<<<NODE_BLOCKS, 256, 0, stream>>>(
            xin, ntype,
            Wk + (size_t)l * TT * DD * DD, bk + (size_t)l * TT * DD,
            Wq + (size_t)l * TT * DD * DD, bq + (size_t)l * TT * DD,
            Wv + (size_t)l * TT * DD * DD, bv + (size_t)l * TT * DD,
            afc_w + (size_t)l * 2 * DKK,
            kbf, qb, vbf, na_q, na_k);

        relpre3_kernel<<<RP3_BLOCKS, 256, 0, stream>>>(
            kbf, vbf,
            rel_att + (size_t)l * RR * HH * 256, rel_msg + (size_t)l * RR * HH * 256,
            k_rel, v_rel);

        edge_logits3_kernel<<<EH_BLOCKS, 256, 0, stream>>>(
            qb, k_rel, src, dst, etype,
            rel_pri + (size_t)l * RR * HH,
            nta + (size_t)l * TT, nta1 + (size_t)l * TT,
            na_q, na_k, wgt + l,
            exbuf, den);

        accum_csr_kernel<<<NODE_BLOCKS, 256, 0, stream>>>(
            v_rel, src, etype, rowptr, eids, exbuf, den, tb);

        float* xout = (l == LL - 1) ? (float*)d_out : ((xin == x0) ? x1 : x0);
        node_out_kernel<<<NODE_BLOCKS, 256, 0, stream>>>(
            xin, tb, den, ntype,
            Wa + (size_t)l * TT * DD * DD, ba + (size_t)l * TT * DD,
            skipp + (size_t)l * TT,
            ln_g + (size_t)l * TT * DD, ln_b + (size_t)l * TT * DD,
            xout);
        xin = xout;
    }
}

// Round 5
// 1150.553 us; speedup vs baseline: 2.8097x; 1.1705x over previous
//
#include <hip/hip_runtime.h>
#include <hip/hip_bf16.h>

#define NN 20000
#define NE 600000
#define DIN 128
#define DD 64
#define HH 4
#define DKK 16
#define LL 4
#define TT 3
#define RR 32
#define RP4_TPW 10                 // tiles (16 nodes) per wave
#define RP4_CH  125                // chunks per r: 125*10*16 = 20000

typedef __attribute__((ext_vector_type(8))) short bf16x8;
typedef __attribute__((ext_vector_type(4))) float f32x4;

__device__ __forceinline__ int src_nt(int e) { return e <= 9 ? 0 : (e <= 21 ? 1 : 2); }
__device__ __forceinline__ int dst_nt(int e) {
    if (e <= 2 || (e >= 10 && e <= 13) || (e >= 22 && e <= 24)) return 0;
    if ((e >= 3 && e <= 6) || (e >= 14 && e <= 17) || (e >= 25 && e <= 28)) return 1;
    return 2;
}
__device__ __forceinline__ float bf_lo(unsigned u) { return __uint_as_float(u << 16); }
__device__ __forceinline__ float bf_hi(unsigned u) { return __uint_as_float(u & 0xffff0000u); }
// round-to-nearest-even f32 -> bf16 bits
__device__ __forceinline__ ushort f2bf(float x) {
    unsigned u = __float_as_uint(x);
    return (ushort)((u + 0x7fffu + ((u >> 16) & 1u)) >> 16);
}

// ---- x = tanh(h @ adapt_W[ntype] + adapt_b[ntype]); wave per node ----
__global__ void adapt_kernel(const float* __restrict__ h, const int* __restrict__ ntype,
                             const float* __restrict__ W, const float* __restrict__ b,
                             float* __restrict__ x) {
    int wid = (blockIdx.x * blockDim.x + threadIdx.x) >> 6;
    int lane = threadIdx.x & 63;
    if (wid >= NN) return;
    int t = ntype[wid];
    const float* Wt = W + (size_t)t * DIN * DD;
    float h0 = h[(size_t)wid * DIN + lane];
    float h1 = h[(size_t)wid * DIN + 64 + lane];
    float acc = b[t * DD + lane];
#pragma unroll
    for (int d = 0; d < 64; ++d) acc += __shfl(h0, d) * Wt[d * DD + lane];
#pragma unroll
    for (int d = 0; d < 64; ++d) acc += __shfl(h1, d) * Wt[(64 + d) * DD + lane];
    x[(size_t)wid * DD + lane] = tanhf(acc);
}

// ---- CSR build: count, scan, fill ----
__global__ void csr_count_kernel(const int* __restrict__ dst, int* __restrict__ cnt) {
    int e = blockIdx.x * blockDim.x + threadIdx.x;
    if (e < NE) atomicAdd(&cnt[dst[e]], 1);
}

__global__ void csr_scan_kernel(const int* __restrict__ cnt, int* __restrict__ rowptr,
                                int* __restrict__ cursor) {
    __shared__ int wsum[16];
    __shared__ int s_carry;
    int tid = threadIdx.x;            // blockDim = 1024
    int lane = tid & 63, wid = tid >> 6;
    if (tid == 0) s_carry = 0;
    __syncthreads();
    for (int base = 0; base < NN; base += 1024) {
        int i = base + tid;
        int v = (i < NN) ? cnt[i] : 0;
        int x = v;
#pragma unroll
        for (int off = 1; off < 64; off <<= 1) {
            int y = __shfl_up(x, off);
            if (lane >= off) x += y;
        }
        if (lane == 63) wsum[wid] = x;
        __syncthreads();
        if (wid == 0 && lane < 16) {
            int w = wsum[lane];
#pragma unroll
            for (int off = 1; off < 16; off <<= 1) {
                int y = __shfl_up(w, off);
                if (lane >= off) w += y;
            }
            wsum[lane] = w;
        }
        __syncthreads();
        int woff = (wid > 0) ? wsum[wid - 1] : 0;
        int carry = s_carry;
        int excl = carry + woff + x - v;
        if (i < NN) { rowptr[i] = excl; cursor[i] = excl; }
        __syncthreads();
        if (tid == 1023) s_carry = carry + wsum[15];
        __syncthreads();
    }
    if (tid == 0) rowptr[NN] = NE;
}

__global__ void csr_fill_kernel(const int* __restrict__ dst, int* __restrict__ cursor,
                                int* __restrict__ eids) {
    int e = blockIdx.x * blockDim.x + threadIdx.x;
    if (e >= NE) return;
    int p = atomicAdd(&cursor[dst[e]], 1);
    eids[p] = e;
}

// ---- k,q,v + na_q/na_k; wave per node; k,v emitted as bf16 ----
__global__ void kqv_kernel(const float* __restrict__ x, const int* __restrict__ ntype,
                           const float* __restrict__ Wk, const float* __restrict__ bk,
                           const float* __restrict__ Wq, const float* __restrict__ bq,
                           const float* __restrict__ Wv, const float* __restrict__ bv,
                           const float* __restrict__ afc,
                           ushort* __restrict__ kbf, float* __restrict__ q, ushort* __restrict__ vbf,
                           float* __restrict__ na_q, float* __restrict__ na_k) {
    int wid = (blockIdx.x * blockDim.x + threadIdx.x) >> 6;
    int lane = threadIdx.x & 63;
    if (wid >= NN) return;
    int t = ntype[wid];
    const float* Wkt = Wk + (size_t)t * DD * DD;
    const float* Wqt = Wq + (size_t)t * DD * DD;
    const float* Wvt = Wv + (size_t)t * DD * DD;
    float xv = x[(size_t)wid * DD + lane];
    float ak = bk[t * DD + lane];
    float aq = bq[t * DD + lane];
    float av = bv[t * DD + lane];
#pragma unroll
    for (int d = 0; d < 64; ++d) {
        float xd = __shfl(xv, d);
        ak += xd * Wkt[d * DD + lane];
        aq += xd * Wqt[d * DD + lane];
        av += xd * Wvt[d * DD + lane];
    }
    kbf[(size_t)wid * DD + lane] = f2bf(ak);
    q[(size_t)wid * DD + lane] = aq;
    vbf[(size_t)wid * DD + lane] = f2bf(av);
    int f = lane & 15;
    float cq = aq * afc[f];
    float ck = ak * afc[16 + f];
#pragma unroll
    for (int off = 1; off < 16; off <<= 1) {
        cq += __shfl_xor(cq, off);
        ck += __shfl_xor(ck, off);
    }
    if (f == 0) {
        na_q[wid * HH + (lane >> 4)] = cq;
        na_k[wid * HH + (lane >> 4)] = ck;
    }
}

// ---- relpre v4: wave owns (r, chunk), ALL 4 h. 8 MFMAs/tile, LDS transpose,
//      full-128B-line stores (no read-for-ownership).
// A-op: lane l, elem j -> rel[r][h][d=(l>>4)*8+j][f=l&15] (zero for d>=16)
// B-op: lane l, elem j -> kbf[n0+(l&15)][h*16 + (l>>4&1)*8 + j]
// D: col(l&15)=node, rows (l>>4)*4+j = f
__global__ __launch_bounds__(256) void relpre4_kernel(
        const ushort* __restrict__ kbf, const ushort* __restrict__ vbf,
        const float* __restrict__ relA, const float* __restrict__ relM,
        ushort* __restrict__ k_rel, ushort* __restrict__ v_rel) {
    __shared__ __align__(16) ushort lds[4][2][16 * DD];   // [wave][K/V][16 nodes x 64]
    int gw = (blockIdx.x * blockDim.x + threadIdx.x) >> 6;
    int lane = threadIdx.x & 63;
    int wv = threadIdx.x >> 6;
    int r = gw / RP4_CH;
    int c = gw % RP4_CH;
    int f = lane & 15;
    int g = lane >> 4;
    int d0 = g * 8;
    bf16x8 aK[HH], aM[HH];
#pragma unroll
    for (int h = 0; h < HH; ++h) {
        bf16x8 zk = {0, 0, 0, 0, 0, 0, 0, 0};
        bf16x8 zm = {0, 0, 0, 0, 0, 0, 0, 0};
        if (d0 < 16) {
            const float* Ab = relA + (size_t)(r * HH + h) * 256;
            const float* Mb = relM + (size_t)(r * HH + h) * 256;
#pragma unroll
            for (int j = 0; j < 8; ++j) {
                zk[j] = (short)f2bf(Ab[(d0 + j) * 16 + f]);
                zm[j] = (short)f2bf(Mb[(d0 + j) * 16 + f]);
            }
        }
        aK[h] = zk; aM[h] = zm;
    }
    int dsafe = d0 & 8;           // 0,8,0,8 — lanes g>=2 multiply zero A
    int nd = lane >> 3;           // store phase: node sub-index 0..7
    int ch = lane & 7;            // 16B chunk within node row
    for (int t = 0; t < RP4_TPW; ++t) {
        int n0 = (c * RP4_TPW + t) * 16;
#pragma unroll
        for (int h = 0; h < HH; ++h) {
            size_t brow = (size_t)(n0 + f) * DD + h * 16 + dsafe;
            bf16x8 bK = *(const bf16x8*)(kbf + brow);
            bf16x8 bV = *(const bf16x8*)(vbf + brow);
            f32x4 z = {0.f, 0.f, 0.f, 0.f};
            f32x4 ck = __builtin_amdgcn_mfma_f32_16x16x32_bf16(aK[h], bK, z, 0, 0, 0);
            f32x4 cv = __builtin_amdgcn_mfma_f32_16x16x32_bf16(aM[h], bV, z, 0, 0, 0);
            ushort4 ok, ov;
            ok.x = f2bf(ck[0]); ok.y = f2bf(ck[1]); ok.z = f2bf(ck[2]); ok.w = f2bf(ck[3]);
            ov.x = f2bf(cv[0]); ov.y = f2bf(cv[1]); ov.z = f2bf(cv[2]); ov.w = f2bf(cv[3]);
            int li = f * DD + h * 16 + g * 4;
            *(ushort4*)&lds[wv][0][li] = ok;
            *(ushort4*)&lds[wv][1][li] = ov;
        }
        asm volatile("s_waitcnt lgkmcnt(0)" ::: "memory");
#pragma unroll
        for (int p = 0; p < 2; ++p) {
            int node = p * 8 + nd;
            uint4 dk = *(const uint4*)&lds[wv][0][node * DD + ch * 8];
            uint4 dv = *(const uint4*)&lds[wv][1][node * DD + ch * 8];
            size_t gb = ((size_t)(n0 + node) * RR + r) * DD + ch * 8;
            *(uint4*)(k_rel + gb) = dk;
            *(uint4*)(v_rel + gb) = dv;
        }
        asm volatile("s_waitcnt lgkmcnt(0)" ::: "memory");
    }
}

// ---- edge pass: thread per (e,h); ex = exp(logit) (no max; logits O(1)) + den ----
__global__ void edge_logits3_kernel(const float* __restrict__ q,
                                    const ushort* __restrict__ k_rel,
                                    const int* __restrict__ src, const int* __restrict__ dst,
                                    const int* __restrict__ et,
                                    const float* __restrict__ pri,
                                    const float* __restrict__ nta, const float* __restrict__ nta1,
                                    const float* __restrict__ na_q, const float* __restrict__ na_k,
                                    const float* __restrict__ wgt,
                                    float* __restrict__ ex_out, float* __restrict__ den) {
    int idx = blockIdx.x * blockDim.x + threadIdx.x;
    if (idx >= NE * HH) return;
    int e = idx >> 2, hh = idx & 3;
    int s = src[e], dd = dst[e], r = et[e];
    const uint4* kr = (const uint4*)(k_rel + ((size_t)s * RR + r) * DD + hh * 16);
    uint4 p0 = kr[0], p1 = kr[1];
    const float4* qp = (const float4*)(q + (size_t)dd * DD + hh * 16);
    float4 q0 = qp[0], q1 = qp[1], q2 = qp[2], q3 = qp[3];
    float att = q0.x * bf_lo(p0.x) + q0.y * bf_hi(p0.x)
              + q0.z * bf_lo(p0.y) + q0.w * bf_hi(p0.y)
              + q1.x * bf_lo(p0.z) + q1.y * bf_hi(p0.z)
              + q1.z * bf_lo(p0.w) + q1.w * bf_hi(p0.w)
              + q2.x * bf_lo(p1.x) + q2.y * bf_hi(p1.x)
              + q2.z * bf_lo(p1.y) + q2.w * bf_hi(p1.y)
              + q3.x * bf_lo(p1.z) + q3.y * bf_hi(p1.z)
              + q3.z * bf_lo(p1.w) + q3.w * bf_hi(p1.w);
    att = att * pri[r * HH + hh] * 0.25f;
    float c = nta1[dst_nt(r)] * na_q[dd * HH + hh] + nta[src_nt(r)] * na_k[s * HH + hh];
    float na = c > 0.f ? c : 0.01f * c;
    float sw = 1.f / (1.f + expf(-wgt[0]));
    float exv = expf(att + sw * na);
    ex_out[idx] = exv;
    atomicAdd(&den[((size_t)dd * RR + r) * HH + hh], exv);
}

// ---- accumulation: wave per dst via CSR, no atomics ----
__global__ void accum_csr_kernel(const ushort* __restrict__ v_rel,
                                 const int* __restrict__ src, const int* __restrict__ et,
                                 const int* __restrict__ rowptr, const int* __restrict__ eids,
                                 const float* __restrict__ ex, const float* __restrict__ den,
                                 float* __restrict__ tacc) {
    int n = (blockIdx.x * blockDim.x + threadIdx.x) >> 6;
    int lane = threadIdx.x & 63;
    if (n >= NN) return;
    int beg = rowptr[n], end = rowptr[n + 1];
    int hh = lane >> 4;
    float acc = 0.f;
    for (int j = beg; j < end; ++j) {
        int e = eids[j];
        int s = src[e], r = et[e];
        float p = ex[(size_t)e * HH + hh];
        float dn = den[((size_t)n * RR + r) * HH + hh];
        float val = bf_lo((unsigned)v_rel[((size_t)s * RR + r) * DD + lane]);
        acc += p * __builtin_amdgcn_rcpf(dn) * val;
    }
    tacc[(size_t)n * DD + lane] = acc;
}

// ---- node finalize ----
__global__ void node_out_kernel(const float* __restrict__ x_in, const float* __restrict__ tacc,
                                const float* __restrict__ den, const int* __restrict__ ntype,
                                const float* __restrict__ Wa, const float* __restrict__ ba,
                                const float* __restrict__ skipp,
                                const float* __restrict__ ln_g, const float* __restrict__ ln_b,
                                float* __restrict__ x_out) {
    int n = (blockIdx.x * blockDim.x + threadIdx.x) >> 6;
    int lane = threadIdx.x & 63;
    if (n >= NN) return;
    int t = ntype[n];
    int pres = 0;
    if (lane < RR) pres = (den[((size_t)n * RR + lane) * HH] > 0.f) ? 1 : 0;
    unsigned long long mask = __ballot(pres != 0);
    float cnt = (float)__popcll(mask);
    float divisor = fmaxf(cnt, 1.0f);
    float tv = tacc[(size_t)n * DD + lane] / divisor;
    const float* Wt = Wa + (size_t)t * DD * DD;
    float acc = ba[t * DD + lane];
#pragma unroll
    for (int d = 0; d < 64; ++d) acc += __shfl(tv, d) * Wt[d * DD + lane];
    float alpha = 1.f / (1.f + expf(-skipp[t]));
    float out = acc * alpha + x_in[(size_t)n * DD + lane] * (1.f - alpha);
    float s = out;
#pragma unroll
    for (int off = 1; off < 64; off <<= 1) s += __shfl_xor(s, off);
    float mu = s * (1.f / 64.f);
    float d0 = out - mu;
    float s2 = d0 * d0;
#pragma unroll
    for (int off = 1; off < 64; off <<= 1) s2 += __shfl_xor(s2, off);
    float var = s2 * (1.f / 64.f);
    float xn = d0 * rsqrtf(var + 1e-5f);
    x_out[(size_t)n * DD + lane] = xn * ln_g[t * DD + lane] + ln_b[t * DD + lane];
}

extern "C" void kernel_launch(void* const* d_in, const int* in_sizes, int n_in,
                              void* d_out, int out_size, void* d_ws, size_t ws_size,
                              hipStream_t stream) {
    const float* h       = (const float*)d_in[0];
    const int*   src     = (const int*)d_in[1];
    const int*   dst     = (const int*)d_in[2];
    const int*   etype   = (const int*)d_in[3];
    const int*   ntype   = (const int*)d_in[4];
    const float* adapt_W = (const float*)d_in[5];
    const float* adapt_b = (const float*)d_in[6];
    const float* Wk      = (const float*)d_in[7];
    const float* bk      = (const float*)d_in[8];
    const float* Wq      = (const float*)d_in[9];
    const float* bq      = (const float*)d_in[10];
    const float* Wv      = (const float*)d_in[11];
    const float* bv      = (const float*)d_in[12];
    const float* Wa      = (const float*)d_in[13];
    const float* ba      = (const float*)d_in[14];
    const float* ln_g    = (const float*)d_in[15];
    const float* ln_b    = (const float*)d_in[16];
    const float* rel_att = (const float*)d_in[17];
    const float* rel_msg = (const float*)d_in[18];
    const float* rel_pri = (const float*)d_in[19];
    const float* nta     = (const float*)d_in[20];
    const float* nta1    = (const float*)d_in[21];
    const float* skipp   = (const float*)d_in[22];
    const float* wgt     = (const float*)d_in[23];
    const float* afc_w   = (const float*)d_in[24];

    char* cur = (char*)d_ws;
    auto alloc = [&](size_t bytes) {
        char* p = cur;
        cur += (bytes + 63) & ~(size_t)63;
        return (void*)p;
    };
    float* x0     = (float*)alloc((size_t)NN * DD * 4);
    float* x1     = (float*)alloc((size_t)NN * DD * 4);
    ushort* kbf   = (ushort*)alloc((size_t)NN * DD * 2);
    float* qb     = (float*)alloc((size_t)NN * DD * 4);
    ushort* vbf   = (ushort*)alloc((size_t)NN * DD * 2);
    float* tb     = (float*)alloc((size_t)NN * DD * 4);
    float* exbuf  = (float*)alloc((size_t)NE * HH * 4);
    float* den    = (float*)alloc((size_t)NN * RR * HH * 4);
    float* na_q   = (float*)alloc((size_t)NN * HH * 4);
    float* na_k   = (float*)alloc((size_t)NN * HH * 4);
    int*   cnt    = (int*)alloc((size_t)NN * 4);
    int*   rowptr = (int*)alloc((size_t)(NN + 1) * 4);
    int*   cursor = (int*)alloc((size_t)NN * 4);
    int*   eids   = (int*)alloc((size_t)NE * 4);
    ushort* k_rel = (ushort*)alloc((size_t)NN * RR * DD * 2);
    ushort* v_rel = (ushort*)alloc((size_t)NN * RR * DD * 2);

    const int NODE_BLOCKS = NN / 4;            // 5000
    const int E_BLOCKS    = (NE + 255) / 256;  // 2344
    const int EH_BLOCKS   = (NE * HH) / 256;   // 9375
    const int RP4_BLOCKS  = (RR * RP4_CH) / 4; // 1000 blocks (4000 waves)

    adapt_kernel<<<NODE_BLOCKS, 256, 0, stream>>>(h, ntype, adapt_W, adapt_b, x0);

    hipMemsetAsync(cnt, 0, (size_t)NN * 4, stream);
    csr_count_kernel<<<E_BLOCKS, 256, 0, stream>>>(dst, cnt);
    csr_scan_kernel<<<1, 1024, 0, stream>>>(cnt, rowptr, cursor);
    csr_fill_kernel<<<E_BLOCKS, 256, 0, stream>>>(dst, cursor, eids);

    float* xin = x0;
    for (int l = 0; l < LL; ++l) {
        hipMemsetAsync(den, 0, (size_t)NN * RR * HH * 4, stream);

        kqv_kernel<<<NODE_BLOCKS, 256, 0, stream>>>(
            xin, ntype,
            Wk + (size_t)l * TT * DD * DD, bk + (size_t)l * TT * DD,
            Wq + (size_t)l * TT * DD * DD, bq + (size_t)l * TT * DD,
            Wv + (size_t)l * TT * DD * DD, bv + (size_t)l * TT * DD,
            afc_w + (size_t)l * 2 * DKK,
            kbf, qb, vbf, na_q, na_k);

        relpre4_kernel<<<RP4_BLOCKS, 256, 0, stream>>>(
            kbf, vbf,
            rel_att + (size_t)l * RR * HH * 256, rel_msg + (size_t)l * RR * HH * 256,
            k_rel, v_rel);

        edge_logits3_kernel<<<EH_BLOCKS, 256, 0, stream>>>(
            qb, k_rel, src, dst, etype,
            rel_pri + (size_t)l * RR * HH,
            nta + (size_t)l * TT, nta1 + (size_t)l * TT,
            na_q, na_k, wgt + l,
            exbuf, den);

        accum_csr_kernel<<<NODE_BLOCKS, 256, 0, stream>>>(
            v_rel, src, etype, rowptr, eids, exbuf, den, tb);

        float* xout = (l == LL - 1) ? (float*)d_out : ((xin == x0) ? x1 : x0);
        node_out_kernel<<<NODE_BLOCKS, 256, 0, stream>>>(
            xin, tb, den, ntype,
            Wa + (size_t)l * TT * DD * DD, ba + (size_t)l * TT * DD,
            skipp + (size_t)l * TT,
            ln_g + (size_t)l * TT * DD, ln_b + (size_t)l * TT * DD,
            xout);
        xin = xout;
    }
}